// Round 11
// baseline (396.929 us; speedup 1.0000x reference)
//
#include <hip/hip_runtime.h>

// ---------------------------------------------------------------------------
// QoSNet fully fused (manual grid barrier): prep -> 32-step GRU (f16 MFMA,
// K=160 augmented) -> BN -> 3-head SELU MLP. 2 launches: kinit + fused.
// fused: 512 blocks x 512 thr, __launch_bounds__(512,4) -> 2 blocks/CU
// (VGPR<=128, LDS union 30.4KB) => all 512 blocks co-resident => manual
// spin barrier is safe; clock64 timeout makes residency failure loud, not
// a hang. __threadfence() = agent fence = buffer_wbl2/inv on gfx950 ->
// correct cross-XCD visibility at each barrier.
// Phase0: max(capa) | f16 weight tables | feats gather | per-block hop hist
// Phase1: R7 kgru verbatim (LPT pairing, hi/lo h, K=160), BN stats atomics
// Phase2: per-block 16-item BN+MLP straight from registers (R9-audited).
// ---------------------------------------------------------------------------

#define BS 8192
#define NL 512
#define ML 32
#define DP 128
#define DR 256
#define NJOB 512
#define ST 172               // phase1 LDS row stride (f16), K=160 + pad

// workspace layout (float offsets)
#define OFF_SUM    64
#define OFF_SSQ    192
#define OFF_BAR    576                       // 3 ints (grid barrier counters)
#define OFF_PERM   640                       // BS ints
#define OFF_BH     (OFF_PERM + BS)           // 512*32 ints
#define OFF_WHH16  (OFF_BH + 16384)          // 49152 f16 = 24576 fl
#define OFF_W1     (OFF_WHH16 + 24576)       // 98304 f16 = 49152 fl
#define OFF_W2     (OFF_W1 + 49152)          // 196608 f16 = 98304 fl
#define OFF_FEATS  (OFF_W2 + 98304)          // BS*ML*4 fl

typedef _Float16 f16x8 __attribute__((ext_vector_type(8)));
typedef float    f32x4 __attribute__((ext_vector_type(4)));

__device__ __forceinline__ float sigmoidf_(float x){ return 1.0f/(1.0f+__expf(-x)); }
__device__ __forceinline__ float tanhf_(float x){
  float t = __expf(-2.0f*fabsf(x));
  float r = (1.0f-t)/(1.0f+t);
  return copysignf(r, x);
}
__device__ __forceinline__ float seluf_(float x){
  const float sc = 1.0507009873554805f, al = 1.6732632423543772f;
  return x > 0.0f ? sc*x : sc*al*(__expf(x)-1.0f);
}

// manual grid barrier: release fence -> arrive -> spin (relaxed agent load,
// s_sleep, ~20ms timeout) -> acquire fence. All blocks co-resident by
// construction (512 = 2/CU x 256 CU).
__device__ __forceinline__ void gbar(int* cnt){
  __syncthreads();
  if (threadIdx.x == 0){
    __threadfence();                         // release: buffer_wbl2
    atomicAdd(cnt, 1);
    long long t0 = clock64();
    while (__hip_atomic_load(cnt, __ATOMIC_RELAXED, __HIP_MEMORY_SCOPE_AGENT) < NJOB){
      __builtin_amdgcn_s_sleep(16);
      if (clock64() - t0 > 50000000LL) break;   // loud fail, not a hang
    }
    __threadfence();                         // acquire: buffer_inv
  }
  __syncthreads();
}

__global__ void kinit(float* ws){
  ws[threadIdx.x] = 0.0f;                    // [0,640): max, SUM, SSQ, BAR
}

struct P0 { int hist[32]; int off[32]; };
struct P1 { _Float16 hHI[2][16*ST]; _Float16 hLO[2][16*ST]; };               // 22016 B
struct P2 { _Float16 x[16*136]; _Float16 h1[16*776];
            float aa[DP]; float bb[DP]; float yacc[48]; };                   // 30400 B
union SMem { P0 p0; P1 p1; P2 p2; };

__launch_bounds__(512, 4)
__global__ void fused(const float* __restrict__ demand, const int* __restrict__ hop,
                      const int* __restrict__ path, const float* __restrict__ avail,
                      const float* __restrict__ capa, const float* __restrict__ loss,
                      const float* __restrict__ whh, const float* __restrict__ wih,
                      const float* __restrict__ bih, const float* __restrict__ bhh,
                      const float* __restrict__ gamma, const float* __restrict__ beta,
                      const float* __restrict__ rW1, const float* __restrict__ rb1,
                      const float* __restrict__ rW2, const float* __restrict__ rb2,
                      const float* __restrict__ rW3, const float* __restrict__ rb3,
                      float* ws, float* __restrict__ out){
  __shared__ SMem sm;
  int* bar = (int*)ws + OFF_BAR;
  const int bid  = blockIdx.x;
  const int tid  = threadIdx.x;
  const int gid  = bid*512 + tid;
  const int w    = tid >> 6;
  const int lane = tid & 63;
  const int lm   = lane & 15;
  const int qd   = lane >> 4;
  const int ch   = w*16 + lm;

  // ======================= PHASE 0: prep =======================
  { // max(capa) -> ws[0] int-bits (kinit zeroed; capa > 0)
    const float4* c4 = (const float4*)capa;
    float m = 0.0f;
    #pragma unroll
    for (int i = gid; i < BS*NL/4; i += 512*512){
      float4 v = c4[i];
      m = fmaxf(m, fmaxf(fmaxf(v.x, v.y), fmaxf(v.z, v.w)));
    }
    #pragma unroll
    for (int o = 32; o > 0; o >>= 1) m = fmaxf(m, __shfl_down(m, o, 64));
    if (lane == 0) atomicMax((int*)ws, __float_as_int(m));
  }

  { // f16 weight tables
    _Float16* whh16 = (_Float16*)(ws + OFF_WHH16);
    _Float16* w1t   = (_Float16*)(ws + OFF_W1);
    _Float16* w2t   = (_Float16*)(ws + OFF_W2);
    if (gid < 49152) whh16[gid] = (_Float16)whh[gid];
    for (int i = gid; i < 294912; i += 262144){
      if (i < 98304){
        int u = i >> 15, rem = i & 32767, n = rem >> 7, k = rem & 127;
        w1t[i] = (_Float16)rW1[u*32768 + k*256 + n];       // w1[u][n][k]
      } else {
        int j = i - 98304;
        int u = j >> 16, rem = j & 65535, n = rem >> 8, k = rem & 255;
        w2t[j] = (_Float16)rW2[u*65536 + k*256 + n];       // w2[u][n][k]
      }
    }
  }

  { // feats gather: one (b,t) per thread, RAW [a, c, a/c, loss]
    int b = gid >> 5, t = gid & 31;
    float4 f = make_float4(0.f, 0.f, 0.f, 0.f);
    if (t < hop[b]){
      int l = path[gid];
      float a = avail[b*NL + l];
      float c = capa [b*NL + l];
      f.x = a; f.y = c; f.z = a / c; f.w = loss[b*NL + l];
    }
    ((float4*)(ws + OFF_FEATS))[gid] = f;
  }

  { // per-block histogram of its 16 items (desc key = 32-hop)
    if (tid < 32) sm.p0.hist[tid] = 0;
    __syncthreads();
    if (tid < 16) atomicAdd(&sm.p0.hist[32 - hop[bid*16 + tid]], 1);
    __syncthreads();
    if (tid < 32) ((int*)ws + OFF_BH)[bid*32 + tid] = sm.p0.hist[tid];
  }

  gbar(&bar[0]);   // ---- bhist/tables/max/feats visible ----

  { // redundant per-block prefix over 512x32 bhist -> scatter own 16 items
    if (tid < 32){
      const int* bh = (const int*)ws + OFF_BH;
      int off = 0, tot = 0;
      for (int b2 = 0; b2 < 512; ++b2){
        int c = bh[b2*32 + tid];
        tot += c;
        if (b2 < bid) off += c;
      }
      int g = tot;
      #pragma unroll
      for (int o = 1; o < 32; o <<= 1){ int v = __shfl_up(g, o, 64); if (tid >= o) g += v; }
      sm.p0.off[tid] = (g - tot) + off;    // gstart[key] + block offset
    }
    __syncthreads();
    if (tid < 16){
      int b = bid*16 + tid;
      int k = 32 - hop[b];
      int rank = 0;
      for (int j = 0; j < 16; ++j)
        rank += ((32 - hop[bid*16 + j]) == k && j < tid) ? 1 : 0;
      ((int*)ws + OFF_PERM)[sm.p0.off[k] + rank] = b;
    }
  }

  gbar(&bar[1]);   // ---- perm ready ----

  // ======================= PHASE 1: GRU (R7 body) =======================
  const float inv_maxc = 1.0f / ws[0];
  const int* perm = (const int*)ws + OFF_PERM;
  const float* feats = ws + OFF_FEATS;
  const _Float16* whh16 = (const _Float16*)(ws + OFF_WHH16);
  const int q = (bid < 256) ? bid : 767 - bid;   // LPT pair on shared CU

  for (int idx = tid; idx < 1024; idx += 512){   // zero pad cols 128..159
    const int buf = idx >> 9, rem = idx & 511;
    const int m = rem >> 5, c = 128 + (rem & 31);
    sm.p1.hHI[buf][m*ST + c] = (_Float16)0.f;
    sm.p1.hLO[buf][m*ST + c] = (_Float16)0.f;
  }

  f16x8 bfr[5], bfz[5], bfnh[4], bfni;
  #pragma unroll
  for (int kc = 0; kc < 4; ++kc){
    bfr[kc]  = *(const f16x8*)(whh16 + (      ch)*128 + kc*32 + qd*8);
    bfz[kc]  = *(const f16x8*)(whh16 + (128 + ch)*128 + kc*32 + qd*8);
    bfnh[kc] = *(const f16x8*)(whh16 + (256 + ch)*128 + kc*32 + qd*8);
  }
  bfr[4] = (f16x8)0; bfz[4] = (f16x8)0; bfni = (f16x8)0;
  if (qd == 0){
    #pragma unroll
    for (int j = 0; j < 4; ++j){
      float s = (j < 2) ? inv_maxc : 1.0f;
      bfr[4][j] = (_Float16)(wih[(      ch)*32 + 28 + j] * s);
      bfz[4][j] = (_Float16)(wih[(128 + ch)*32 + 28 + j] * s);
      bfni[j]   = (_Float16)(wih[(256 + ch)*32 + 28 + j] * s);
    }
  }
  const float bR  = bih[ch]     + bhh[ch];
  const float bZ  = bih[128+ch] + bhh[128+ch];
  const float bNI = bih[256+ch];
  const float bNH = bhh[256+ch];

  int it[4], hp[4];
  #pragma unroll
  for (int r = 0; r < 4; ++r){
    it[r] = perm[q*16 + qd*4 + r];
    hp[r] = hop[it[r]];
  }
  int tmax = max(max(hp[0],hp[1]), max(hp[2],hp[3]));
  tmax = max(tmax, __shfl_xor(tmax, 16, 64));
  tmax = max(tmax, __shfl_xor(tmax, 32, 64));

  const int  fw_i = w*2 + (lane >> 2);
  const int  fw_c = lane & 3;
  const bool fw   = (lane < 8);
  const int  fw_b = fw ? perm[q*16 + fw_i] : 0;

  __syncthreads();   // pad zero complete before feature writes

  float hprev[4];
  #pragma unroll
  for (int r = 0; r < 4; ++r){
    float h0 = (ch == 127) ? demand[it[r]] * inv_maxc : 0.0f;
    hprev[r] = h0;
    const int m = qd*4 + r;
    _Float16 hi = (_Float16)h0;
    sm.p1.hHI[0][m*ST + ch] = hi;
    sm.p1.hLO[0][m*ST + ch] = (_Float16)(h0 - (float)hi);
  }
  if (fw){
    float v = feats[(fw_b*ML + 0)*4 + fw_c];
    _Float16 hi = (_Float16)v;
    sm.p1.hHI[0][fw_i*ST + 128 + fw_c] = hi;
    sm.p1.hLO[0][fw_i*ST + 128 + fw_c] = (_Float16)(v - (float)hi);
  }
  __syncthreads();

  for (int t = 0; t < tmax; ++t){
    const int cur = t & 1, nxt = cur ^ 1;
    if (fw && (t+1) < ML){
      float v = feats[(fw_b*ML + t + 1)*4 + fw_c];
      _Float16 hi = (_Float16)v;
      sm.p1.hHI[nxt][fw_i*ST + 128 + fw_c] = hi;
      sm.p1.hLO[nxt][fw_i*ST + 128 + fw_c] = (_Float16)(v - (float)hi);
    }

    f32x4 accr = {0.f,0.f,0.f,0.f}, accz = {0.f,0.f,0.f,0.f};
    f32x4 accnh = {0.f,0.f,0.f,0.f}, accni = {0.f,0.f,0.f,0.f};
    #pragma unroll
    for (int kc = 0; kc < 5; ++kc){
      const int off = lm*ST + kc*32 + qd*8;
      f16x8 ahi = *(const f16x8*)(&sm.p1.hHI[cur][off]);
      f16x8 alo = *(const f16x8*)(&sm.p1.hLO[cur][off]);
      accr = __builtin_amdgcn_mfma_f32_16x16x32_f16(ahi, bfr[kc], accr, 0, 0, 0);
      accr = __builtin_amdgcn_mfma_f32_16x16x32_f16(alo, bfr[kc], accr, 0, 0, 0);
      accz = __builtin_amdgcn_mfma_f32_16x16x32_f16(ahi, bfz[kc], accz, 0, 0, 0);
      accz = __builtin_amdgcn_mfma_f32_16x16x32_f16(alo, bfz[kc], accz, 0, 0, 0);
      if (kc < 4){
        accnh = __builtin_amdgcn_mfma_f32_16x16x32_f16(ahi, bfnh[kc], accnh, 0, 0, 0);
        accnh = __builtin_amdgcn_mfma_f32_16x16x32_f16(alo, bfnh[kc], accnh, 0, 0, 0);
      } else {
        accni = __builtin_amdgcn_mfma_f32_16x16x32_f16(ahi, bfni, accni, 0, 0, 0);
        accni = __builtin_amdgcn_mfma_f32_16x16x32_f16(alo, bfni, accni, 0, 0, 0);
      }
    }

    #pragma unroll
    for (int r = 0; r < 4; ++r){
      float rr = sigmoidf_(accr[r] + bR);
      float zz = sigmoidf_(accz[r] + bZ);
      float nn = tanhf_(accni[r] + bNI + rr*(accnh[r] + bNH));
      float hn = fmaf(zz, hprev[r] - nn, nn);
      if (t < hp[r]) hprev[r] = hn;
      const int m = qd*4 + r;
      _Float16 hi = (_Float16)hprev[r];
      sm.p1.hHI[nxt][m*ST + ch] = hi;
      sm.p1.hLO[nxt][m*ST + ch] = (_Float16)(hprev[r] - (float)hi);
    }
    __syncthreads();
  }

  { // BN stats
    float ssum = 0.f, ssq = 0.f;
    #pragma unroll
    for (int r = 0; r < 4; ++r){ ssum += hprev[r]; ssq = fmaf(hprev[r], hprev[r], ssq); }
    ssum += __shfl_xor(ssum, 16, 64);  ssum += __shfl_xor(ssum, 32, 64);
    ssq  += __shfl_xor(ssq,  16, 64);  ssq  += __shfl_xor(ssq,  32, 64);
    if (qd == 0){
      atomicAdd(&ws[OFF_SUM + ch], ssum);
      atomicAdd(&ws[OFF_SSQ + ch], ssq);
    }
  }

  gbar(&bar[2]);   // ---- BN stats complete ----

  // ======================= PHASE 2: BN + MLP =======================
  if (tid < DP){
    float m  = ws[OFF_SUM + tid] * (1.0f/BS);
    float qq = ws[OFF_SSQ + tid] * (1.0f/BS);
    float rstd = rsqrtf(qq - m*m + 1e-5f);
    float a = rstd * gamma[tid];
    sm.p2.aa[tid] = a;
    sm.p2.bb[tid] = fmaf(-m, a, beta[tid]);
  }
  if (tid < 48) sm.p2.yacc[tid] = 0.f;
  __syncthreads();

  #pragma unroll
  for (int r = 0; r < 4; ++r)   // x[m][ch] = BN(h) from registers
    sm.p2.x[(qd*4 + r)*136 + ch] =
      (_Float16)fmaf(hprev[r], sm.p2.aa[ch], sm.p2.bb[ch]);
  __syncthreads();

  { // L1: 16 x 128 @ 128 x (3*256): 48 n-tiles, wave w -> nt = w + 8*ti
    const _Float16* w1t = (const _Float16*)(ws + OFF_W1);
    f16x8 a1[4];
    #pragma unroll
    for (int kc = 0; kc < 4; ++kc)
      a1[kc] = *(const f16x8*)(&sm.p2.x[lm*136 + kc*32 + qd*8]);
    #pragma unroll
    for (int ti = 0; ti < 6; ++ti){
      const int nt = w + ti*8;
      const int u  = nt >> 4;
      const int nl = ((nt & 15) << 4) + lm;
      const float b1v = rb1[u*DR + nl];
      f16x8 bf1[4];
      #pragma unroll
      for (int kc = 0; kc < 4; ++kc)
        bf1[kc] = *(const f16x8*)(w1t + u*32768 + nl*128 + kc*32 + qd*8);
      f32x4 acc = {b1v, b1v, b1v, b1v};
      #pragma unroll
      for (int kc = 0; kc < 4; ++kc)
        acc = __builtin_amdgcn_mfma_f32_16x16x32_f16(a1[kc], bf1[kc], acc, 0, 0, 0);
      #pragma unroll
      for (int r = 0; r < 4; ++r)
        sm.p2.h1[(qd*4 + r)*776 + nt*16 + lm] = (_Float16)seluf_(acc[r]);
    }
  }
  __syncthreads();

  { // L2 + w3 dot: per-tile lane reduce, LDS-atomic into yacc[u][m]
    const _Float16* w2t = (const _Float16*)(ws + OFF_W2);
    #pragma unroll
    for (int ti = 0; ti < 6; ++ti){
      const int nt = w + ti*8;
      const int u  = nt >> 4;
      const int nl = ((nt & 15) << 4) + lm;
      const float b2v = rb2[u*DR + nl];
      const float w3v = rW3[u*DR + nl];
      f32x4 acc = {b2v, b2v, b2v, b2v};
      #pragma unroll
      for (int kc = 0; kc < 8; ++kc){
        f16x8 a2  = *(const f16x8*)(&sm.p2.h1[lm*776 + u*256 + kc*32 + qd*8]);
        f16x8 bf2 = *(const f16x8*)(w2t + u*65536 + nl*256 + kc*32 + qd*8);
        acc = __builtin_amdgcn_mfma_f32_16x16x32_f16(a2, bf2, acc, 0, 0, 0);
      }
      #pragma unroll
      for (int r = 0; r < 4; ++r){
        float v = seluf_(acc[r]) * w3v;
        v += __shfl_xor(v, 1, 64);
        v += __shfl_xor(v, 2, 64);
        v += __shfl_xor(v, 4, 64);
        v += __shfl_xor(v, 8, 64);
        if (lm == 0) atomicAdd(&sm.p2.yacc[u*16 + qd*4 + r], v);
      }
    }
  }
  __syncthreads();

  if (tid < 48){
    const int u = tid >> 4, m = tid & 15;
    const int item = ((const int*)ws + OFF_PERM)[q*16 + m];
    out[item*3 + u] = sm.p2.yacc[tid] + rb3[u];
  }
}

extern "C" void kernel_launch(void* const* d_in, const int* in_sizes, int n_in,
                              void* d_out, int out_size, void* d_ws, size_t ws_size,
                              hipStream_t stream){
  const float* demand = (const float*)d_in[0];
  const float* avail  = (const float*)d_in[1];
  const float* capa   = (const float*)d_in[2];
  const float* loss   = (const float*)d_in[3];
  const int*   path   = (const int*)d_in[4];
  const int*   hop    = (const int*)d_in[5];
  const float* wih    = (const float*)d_in[6];
  const float* whh    = (const float*)d_in[7];
  const float* bih    = (const float*)d_in[8];
  const float* bhh    = (const float*)d_in[9];
  const float* gamma  = (const float*)d_in[10];
  const float* beta   = (const float*)d_in[11];
  const float* rW1    = (const float*)d_in[12];
  const float* rb1    = (const float*)d_in[13];
  const float* rW2    = (const float*)d_in[14];
  const float* rb2    = (const float*)d_in[15];
  const float* rW3    = (const float*)d_in[16];
  const float* rb3    = (const float*)d_in[17];
  float* ws  = (float*)d_ws;
  float* out = (float*)d_out;

  kinit <<<1, 640, 0, stream>>>(ws);
  fused <<<NJOB, 512, 0, stream>>>(demand, hop, path, avail, capa, loss,
                                   whh, wih, bih, bhh, gamma, beta,
                                   rW1, rb1, rW2, rb2, rW3, rb3, ws, out);
}

// Round 12
// 203.237 us; speedup vs baseline: 1.9530x; 1.9530x over previous
//
#include <hip/hip_runtime.h>

// ---------------------------------------------------------------------------
// QoSNet: gather -> 32-step GRU(D=128) -> batchnorm -> 3x SELU MLP readout
// BS=8192, N_LINKS=512, MAX_LEN=32, D_PATH=128, D_READ=256, N_OUT=3.
// R12 = R10 with kgru slimmed:
//   - single-f16 h (lo-half dropped): 15 MFMA/wave/step instead of 30,
//     half the cvt + ds_write epilogue. absmax budget 6x allows it.
//   - rcp-based sigmoid/tanh (v_rcp_f32) instead of full-precision divides.
// prep_all and kmlp are bit-identical to R10.
// Known fixed floor: ~100 us of harness-side timed overhead (measured R11:
// 2-launch round had 397 total with 297+2 in kernels).
// ---------------------------------------------------------------------------

#define BS 8192
#define NL 512
#define ML 32
#define DP 128
#define DR 256
#define NJOB 512             // 16 items per job
#define ST 172               // LDS row stride (f16) for K=160 + pad

// workspace layout (float offsets into d_ws)
#define OFF_SUM    64
#define OFF_SSQ    192
#define OFF_CUR    576
#define OFF_PERM   640                      // BS ints
#define OFF_WHH16  (OFF_PERM + BS)          // 49152 f16  = 24576 fl
#define OFF_W1     (OFF_WHH16 + 24576)      // 98304 f16  = 49152 fl
#define OFF_W2     (OFF_W1 + 49152)         // 196608 f16 = 98304 fl
#define OFF_FEATS  (OFF_W2 + 98304)         // BS*ML*4 fl
#define OFF_FLOW   (OFF_FEATS + BS*ML*4)    // BS*DP fl

// prep_all role partition (256-thr blocks)
#define FEATS_BLOCKS 1024
#define MAX_BLOCKS   256
#define WPREP_BLOCKS 1344    // (49152+98304+196608)/256
#define SORT_BID     (FEATS_BLOCKS + MAX_BLOCKS + WPREP_BLOCKS)   // 2624
#define PREP_GRID    (SORT_BID + 1)

typedef _Float16 f16x8 __attribute__((ext_vector_type(8)));
typedef float    f32x4 __attribute__((ext_vector_type(4)));

__device__ __forceinline__ float sigmoidf_(float x){
  return __builtin_amdgcn_rcpf(1.0f + __expf(-x));
}
__device__ __forceinline__ float tanhf_(float x){
  float t = __expf(-2.0f*fabsf(x));
  float r = (1.0f - t) * __builtin_amdgcn_rcpf(1.0f + t);
  return copysignf(r, x);
}
__device__ __forceinline__ float seluf_(float x){
  const float sc = 1.0507009873554805f, al = 1.6732632423543772f;
  return x > 0.0f ? sc*x : sc*al*(__expf(x)-1.0f);
}

// ---------------------------------------------------------------------------
// prep_all: independent roles by blockIdx.x (R10 verbatim).
// ---------------------------------------------------------------------------
__global__ void prep_all(const int* __restrict__ path, const int* __restrict__ hop,
                         const float* __restrict__ avail, const float* __restrict__ capa,
                         const float* __restrict__ loss, const float* __restrict__ whh,
                         const float* __restrict__ rW1, const float* __restrict__ rW2,
                         float* ws){
  const int bid = blockIdx.x;
  const int tid = threadIdx.x;

  if (bid < FEATS_BLOCKS){                       // ---- feats gather ----
    int idx = bid*256 + tid;                     // over BS*ML
    int b = idx >> 5, t = idx & 31;
    float4 f = make_float4(0.f, 0.f, 0.f, 0.f);
    if (t < hop[b]){
      int l = path[idx];
      float a = avail[b*NL + l];
      float c = capa [b*NL + l];
      f.x = a; f.y = c; f.z = a / c; f.w = loss[b*NL + l];
    }
    ((float4*)(ws + OFF_FEATS))[idx] = f;
  } else if (bid < FEATS_BLOCKS + MAX_BLOCKS){   // ---- global max(capa) ----
    const float4* c4 = (const float4*)capa;
    const int n4 = BS*NL/4;
    float m = 0.0f;
    for (int i = (bid - FEATS_BLOCKS)*256 + tid; i < n4; i += MAX_BLOCKS*256){
      float4 v = c4[i];
      m = fmaxf(m, fmaxf(fmaxf(v.x, v.y), fmaxf(v.z, v.w)));
    }
    #pragma unroll
    for (int o = 32; o > 0; o >>= 1) m = fmaxf(m, __shfl_down(m, o, 64));
    if ((tid & 63) == 0) atomicMax((int*)ws, __float_as_int(m));
  } else if (bid < SORT_BID){                    // ---- f16 weight tables ----
    _Float16* whh16 = (_Float16*)(ws + OFF_WHH16);
    _Float16* w1    = (_Float16*)(ws + OFF_W1);
    _Float16* w2    = (_Float16*)(ws + OFF_W2);
    int i = (bid - FEATS_BLOCKS - MAX_BLOCKS)*256 + tid;
    if (i < 49152){
      whh16[i] = (_Float16)whh[i];
    } else if (i < 147456){
      int j = i - 49152; int u = j >> 15; int rem = j & 32767; int n = rem >> 7; int k = rem & 127;
      w1[j] = (_Float16)rW1[u*32768 + k*256 + n];
    } else if (i < 344064){
      int j = i - 147456; int u = j >> 16; int rem = j & 65535; int n = rem >> 8; int k = rem & 255;
      w2[j] = (_Float16)rW2[u*65536 + k*256 + n];
    }
  } else {                                       // ---- zero ctrl + hop sort ----
    __shared__ int hist[32], start[32];
    for (int i = 64 + tid; i < 640; i += 256) ws[i] = 0.0f;   // SUM/SSQ/CUR
    if (tid < 32) hist[tid] = 0;
    __syncthreads();
    for (int b = tid; b < BS; b += 256) atomicAdd(&hist[32 - hop[b]], 1);  // desc key
    __syncthreads();
    if (tid == 0){ int acc = 0; for (int i = 0; i < 32; ++i){ start[i] = acc; acc += hist[i]; } }
    __syncthreads();
    int* perm = (int*)ws + OFF_PERM;
    for (int b = tid; b < BS; b += 256){
      int pos = atomicAdd(&start[32 - hop[b]], 1);
      perm[pos] = b;
    }
  }
}

// ---------------------------------------------------------------------------
// GRU via MFMA, K=160 augmented A (cols 0..127 h, 128..131 feats, rest 0).
// R12: single-f16 h (no lo pair): accr/accz get 5 MFMAs, accnh 4, accni 1.
// Block = 512 thr = 8 waves = one 16-item hop-uniform job; wave owns 16 ch.
// Static LPT pairing: blocks i and 767-bid share a CU -> jobs i and 511-i.
// ---------------------------------------------------------------------------
__launch_bounds__(512, 4)
__global__ void kgru(const float* __restrict__ demand, const int* __restrict__ hop,
                     const float* __restrict__ wih, const float* __restrict__ bih,
                     const float* __restrict__ bhh, float* __restrict__ ws,
                     float* __restrict__ flow){
  __shared__ _Float16 hA[2][16*ST];
  const int tid  = threadIdx.x;
  const int w    = tid >> 6;          // 0..7
  const int lane = tid & 63;
  const int lm   = lane & 15;
  const int qd   = lane >> 4;
  const int ch   = w*16 + lm;         // channel owned
  const float inv_maxc = 1.0f / ws[0];
  const int* perm = (const int*)ws + OFF_PERM;
  const float* feats = ws + OFF_FEATS;
  const _Float16* whh16 = (const _Float16*)(ws + OFF_WHH16);

  const int bid = blockIdx.x;
  const int q = (bid < 256) ? bid : 767 - bid;   // LPT pair on shared CU

  // zero pad/feature cols 128..159, both buffers, before any feature write
  for (int idx = tid; idx < 1024; idx += 512){
    const int buf = idx >> 9;
    const int rem = idx & 511;
    const int m   = rem >> 5;
    const int c   = 128 + (rem & 31);
    hA[buf][m*ST + c] = (_Float16)0.f;
  }

  // B~ fragments (register-resident)
  f16x8 bfr[5], bfz[5], bfnh[4], bfni;
  #pragma unroll
  for (int kc = 0; kc < 4; ++kc){
    bfr[kc]  = *(const f16x8*)(whh16 + (      ch)*128 + kc*32 + qd*8);
    bfz[kc]  = *(const f16x8*)(whh16 + (128 + ch)*128 + kc*32 + qd*8);
    bfnh[kc] = *(const f16x8*)(whh16 + (256 + ch)*128 + kc*32 + qd*8);
  }
  bfr[4] = (f16x8)0; bfz[4] = (f16x8)0; bfni = (f16x8)0;
  if (qd == 0){
    #pragma unroll
    for (int j = 0; j < 4; ++j){
      float s = (j < 2) ? inv_maxc : 1.0f;
      bfr[4][j] = (_Float16)(wih[(      ch)*32 + 28 + j] * s);
      bfz[4][j] = (_Float16)(wih[(128 + ch)*32 + 28 + j] * s);
      bfni[j]   = (_Float16)(wih[(256 + ch)*32 + 28 + j] * s);
    }
  }
  const float bR  = bih[ch]     + bhh[ch];
  const float bZ  = bih[128+ch] + bhh[128+ch];
  const float bNI = bih[256+ch];
  const float bNH = bhh[256+ch];

  // job items (per quad: 4 items)
  int it[4], hp[4];
  #pragma unroll
  for (int r = 0; r < 4; ++r){
    it[r] = perm[q*16 + qd*4 + r];
    hp[r] = hop[it[r]];
  }
  int tmax = max(max(hp[0],hp[1]), max(hp[2],hp[3]));
  tmax = max(tmax, __shfl_xor(tmax, 16, 64));
  tmax = max(tmax, __shfl_xor(tmax, 32, 64));

  // feature-writer lanes: 8 per wave (item = w*2 + lane>>2, c = lane&3)
  const int fw_i = w*2 + (lane >> 2);
  const int fw_c = lane & 3;
  const bool fw  = (lane < 8);
  const int  fw_b = fw ? perm[q*16 + fw_i] : 0;

  __syncthreads();   // pad zeroing complete before feature writes

  // init: h0 (cols 0..127) + features(t=0)
  float hprev[4];
  #pragma unroll
  for (int r = 0; r < 4; ++r){
    float h0 = (ch == 127) ? demand[it[r]] * inv_maxc : 0.0f;
    hprev[r] = h0;
    hA[0][(qd*4 + r)*ST + ch] = (_Float16)h0;
  }
  if (fw)
    hA[0][fw_i*ST + 128 + fw_c] = (_Float16)feats[(fw_b*ML + 0)*4 + fw_c];
  __syncthreads();

  for (int t = 0; t < tmax; ++t){
    const int cur = t & 1, nxt = cur ^ 1;
    if (fw && (t+1) < ML)
      hA[nxt][fw_i*ST + 128 + fw_c] = (_Float16)feats[(fw_b*ML + t + 1)*4 + fw_c];

    f32x4 accr = {0.f,0.f,0.f,0.f}, accz = {0.f,0.f,0.f,0.f};
    f32x4 accnh = {0.f,0.f,0.f,0.f}, accni = {0.f,0.f,0.f,0.f};
    #pragma unroll
    for (int kc = 0; kc < 5; ++kc){
      f16x8 a = *(const f16x8*)(&hA[cur][lm*ST + kc*32 + qd*8]);
      accr = __builtin_amdgcn_mfma_f32_16x16x32_f16(a, bfr[kc], accr, 0, 0, 0);
      accz = __builtin_amdgcn_mfma_f32_16x16x32_f16(a, bfz[kc], accz, 0, 0, 0);
      if (kc < 4)
        accnh = __builtin_amdgcn_mfma_f32_16x16x32_f16(a, bfnh[kc], accnh, 0, 0, 0);
      else
        accni = __builtin_amdgcn_mfma_f32_16x16x32_f16(a, bfni, accni, 0, 0, 0);
    }

    #pragma unroll
    for (int r = 0; r < 4; ++r){
      float rr = sigmoidf_(accr[r] + bR);
      float zz = sigmoidf_(accz[r] + bZ);
      float nn = tanhf_(accni[r] + bNI + rr*(accnh[r] + bNH));
      float hn = fmaf(zz, hprev[r] - nn, nn);          // (1-z)*n + z*h
      if (t < hp[r]) hprev[r] = hn;                    // freeze finished items
      hA[nxt][(qd*4 + r)*ST + ch] = (_Float16)hprev[r];
    }
    __syncthreads();
  }

  float ssum = 0.f, ssq = 0.f;
  #pragma unroll
  for (int r = 0; r < 4; ++r){
    float v = hprev[r];
    flow[it[r]*DP + ch] = v;
    ssum += v;
    ssq  = fmaf(v, v, ssq);
  }
  ssum += __shfl_xor(ssum, 16, 64);  ssum += __shfl_xor(ssum, 32, 64);
  ssq  += __shfl_xor(ssq,  16, 64);  ssq  += __shfl_xor(ssq,  32, 64);
  if (qd == 0){
    atomicAdd(&ws[OFF_SUM + ch], ssum);
    atomicAdd(&ws[OFF_SSQ + ch], ssq);
  }
}

// ---------------------------------------------------------------------------
// BN-finalize + 3-headed MLP via MFMA (R10 verbatim).
// ---------------------------------------------------------------------------
__launch_bounds__(256, 4)
__global__ void kmlp(const float* __restrict__ flow, const float* __restrict__ ws,
                     const float* __restrict__ gamma, const float* __restrict__ beta,
                     const float* __restrict__ rb1, const float* __restrict__ rb2,
                     const float* __restrict__ rW3, const float* __restrict__ rb3,
                     float* __restrict__ out){
  __shared__ _Float16 x_lds[32*136];
  __shared__ _Float16 h1_lds[32*264];
  __shared__ float aa[DP], bb[DP];
  __shared__ float y_part[4][32];
  const int tid  = threadIdx.x;
  const int w    = tid >> 6;
  const int lane = tid & 63;
  const int lm   = lane & 15;
  const int qd   = lane >> 4;
  const int b0   = blockIdx.x * 32;
  const int u    = blockIdx.y;
  const _Float16* w1 = (const _Float16*)(ws + OFF_W1) + u*(DR*DP);
  const _Float16* w2 = (const _Float16*)(ws + OFF_W2) + u*(DR*DR);

  if (tid < DP){                                // BN finalize (redundant/block)
    float m = ws[OFF_SUM + tid] * (1.0f/BS);
    float q = ws[OFF_SSQ + tid] * (1.0f/BS);
    float rstd = rsqrtf(q - m*m + 1e-5f);
    float a = rstd * gamma[tid];
    aa[tid] = a;
    bb[tid] = fmaf(-m, a, beta[tid]);
  }
  __syncthreads();

  for (int idx = tid; idx < 32*DP; idx += 256){
    int i = idx >> 7, h = idx & 127;
    x_lds[i*136 + h] = (_Float16)fmaf(flow[(b0 + i)*DP + h], aa[h], bb[h]);
  }
  __syncthreads();

  // ---- L1: 32x128 @ 128x256 -> selu -> h1_lds ----
  for (int nt = 0; nt < 4; ++nt){
    const int n = (4*w + nt)*16 + lm;
    const float bias1 = rb1[u*DR + n];
    f16x8 b1[4];
    #pragma unroll
    for (int kc = 0; kc < 4; ++kc)
      b1[kc] = *(const f16x8*)(w1 + n*DP + kc*32 + qd*8);
    #pragma unroll
    for (int mt = 0; mt < 2; ++mt){
      f32x4 acc = {bias1, bias1, bias1, bias1};
      #pragma unroll
      for (int kc = 0; kc < 4; ++kc){
        f16x8 a1 = *(const f16x8*)(&x_lds[(mt*16 + lm)*136 + kc*32 + qd*8]);
        acc = __builtin_amdgcn_mfma_f32_16x16x32_f16(a1, b1[kc], acc, 0, 0, 0);
      }
      #pragma unroll
      for (int r = 0; r < 4; ++r)
        h1_lds[(mt*16 + qd*4 + r)*264 + n] = (_Float16)seluf_(acc[r]);
    }
  }
  __syncthreads();

  // ---- L2: 32x256 @ 256x256 -> selu -> dot w3 (in-wave reduce) ----
  {
    float p[2][4] = {{0.f,0.f,0.f,0.f},{0.f,0.f,0.f,0.f}};
    for (int nt = 0; nt < 4; ++nt){
      const int n = (4*w + nt)*16 + lm;
      const float bias2 = rb2[u*DR + n];
      const float w3l   = rW3[u*DR + n];
      f16x8 b2[8];
      #pragma unroll
      for (int kc = 0; kc < 8; ++kc)
        b2[kc] = *(const f16x8*)(w2 + n*DR + kc*32 + qd*8);
      #pragma unroll
      for (int mt = 0; mt < 2; ++mt){
        f32x4 acc = {bias2, bias2, bias2, bias2};
        #pragma unroll
        for (int kc = 0; kc < 8; ++kc){
          f16x8 a2 = *(const f16x8*)(&h1_lds[(mt*16 + lm)*264 + kc*32 + qd*8]);
          acc = __builtin_amdgcn_mfma_f32_16x16x32_f16(a2, b2[kc], acc, 0, 0, 0);
        }
        #pragma unroll
        for (int r = 0; r < 4; ++r)
          p[mt][r] += seluf_(acc[r]) * w3l;
      }
    }
    #pragma unroll
    for (int mt = 0; mt < 2; ++mt){
      #pragma unroll
      for (int r = 0; r < 4; ++r){
        float v = p[mt][r];
        v += __shfl_xor(v, 1, 64);
        v += __shfl_xor(v, 2, 64);
        v += __shfl_xor(v, 4, 64);
        v += __shfl_xor(v, 8, 64);
        if (lm == 0) y_part[w][mt*16 + qd*4 + r] = v;
      }
    }
  }
  __syncthreads();
  if (tid < 32){
    float y = y_part[0][tid] + y_part[1][tid] + y_part[2][tid] + y_part[3][tid] + rb3[u];
    out[(b0 + tid)*3 + u] = y;
  }
}

extern "C" void kernel_launch(void* const* d_in, const int* in_sizes, int n_in,
                              void* d_out, int out_size, void* d_ws, size_t ws_size,
                              hipStream_t stream){
  const float* demand = (const float*)d_in[0];
  const float* avail  = (const float*)d_in[1];
  const float* capa   = (const float*)d_in[2];
  const float* loss   = (const float*)d_in[3];
  const int*   path   = (const int*)d_in[4];
  const int*   hop    = (const int*)d_in[5];
  const float* wih    = (const float*)d_in[6];
  const float* whh    = (const float*)d_in[7];
  const float* bih    = (const float*)d_in[8];
  const float* bhh    = (const float*)d_in[9];
  const float* gamma  = (const float*)d_in[10];
  const float* beta   = (const float*)d_in[11];
  const float* rW1    = (const float*)d_in[12];
  const float* rb1    = (const float*)d_in[13];
  const float* rW2    = (const float*)d_in[14];
  const float* rb2    = (const float*)d_in[15];
  const float* rW3    = (const float*)d_in[16];
  const float* rb3    = (const float*)d_in[17];
  float* ws  = (float*)d_ws;
  float* out = (float*)d_out;

  prep_all <<<PREP_GRID, 256, 0, stream>>>(path, hop, avail, capa, loss,
                                           whh, rW1, rW2, ws);
  kgru     <<<NJOB, 512, 0, stream>>>(demand, hop, wih, bih, bhh, ws, ws + OFF_FLOW);
  kmlp     <<<dim3(BS/32, 3), 256, 0, stream>>>(ws + OFF_FLOW, ws, gamma, beta,
                                                rb1, rb2, rW3, rb3, out);
}